// Round 7
// baseline (3349.894 us; speedup 1.0000x reference)
//
#include <hip/hip_runtime.h>
#include <cstdint>
#include <cstddef>

#define NNODE 118
#define TSEQ  2048
#define TC    256         // chunk length
#define NCH   8
#define TGB   8           // timesteps per gateproj block
#define NEGC  -1000000000.0f

typedef __fp16 f16x8 __attribute__((ext_vector_type(8)));
typedef float floatx4 __attribute__((ext_vector_type(4)));

__device__ __forceinline__ float leakyf(float x){ return x >= 0.f ? x : 0.01f * x; }
__device__ __forceinline__ float frcp(float x){ return __builtin_amdgcn_rcpf(x); }
__device__ __forceinline__ float sigm(float x){ return frcp(1.f + __expf(-x)); }
__device__ __forceinline__ float tanhfast(float x){ return 1.f - 2.f * frcp(__expf(2.f * x) + 1.f); }

// byte offset of (row, colByte) in a 16x256B tile; XOR swizzle spreads the 16
// rows across distinct 16B/32B bank groups (2B scatter writes -> 2 lanes/bank).
__device__ __forceinline__ int swzb(int row, int colByte){
  return row * 256 + (colByte ^ ((row & 7) << 4) ^ ((row & 8) << 2));
}

__device__ float bred_sum(float v, float* buf, int nthr){
  int tid = threadIdx.x;
  buf[tid] = v; __syncthreads();
  for (int s = nthr >> 1; s > 0; s >>= 1){
    if (tid < s) buf[tid] += buf[tid + s];
    __syncthreads();
  }
  float r = buf[0]; __syncthreads(); return r;
}
__device__ float bred_max(float v, float* buf, int nthr){
  int tid = threadIdx.x;
  buf[tid] = v; __syncthreads();
  for (int s = nthr >> 1; s > 0; s >>= 1){
    if (tid < s) buf[tid] = fmaxf(buf[tid], buf[tid + s]);
    __syncthreads();
  }
  float r = buf[0]; __syncthreads(); return r;
}

// ---------------- converts ----------------
__global__ void f32_to_f16_k(const float* __restrict__ in, __fp16* __restrict__ out, int n){
  int i = blockIdx.x * blockDim.x + threadIdx.x;
  if (i < n) out[i] = (__fp16)in[i];
}

// ---------------- gate projection (parallel over t) ----------------
// Blocks [0, n1): pre1[t] = x(t) @ W_ih0^T   (reads f32 x, converts+swizzles)
// Blocks [n1,..): pre2[t] = h1(t) @ W_ih1^T  (reads swizzled f16 ring verbatim)
// Output layout [t][blk][wave(8)][lane(64)][gate-frag(4) x 8B]: a scan thread's
// 4 C-fragments are one contiguous 32B -> 2x dwordx4, fully coalesced per wave.
__global__ __launch_bounds__(256, 2) void gateproj(
    const float* __restrict__ x,
    const __fp16* __restrict__ ringr,
    const __fp16* __restrict__ wiA,      // W_ih0 f16 [512][128]
    const __fp16* __restrict__ wiB,      // W_ih1 f16 [512][128]
    __fp16* __restrict__ pre1o, __fp16* __restrict__ pre2o,
    int n1blocks, int t0abs)
{
  const int tid = threadIdx.x, lane = tid & 63, w4 = tid >> 6;
  const int q = lane >> 4, l16 = lane & 15;
  const bool isA = (int)blockIdx.x < n1blocks;
  const int bid = isA ? blockIdx.x : (blockIdx.x - n1blocks);
  const int tg = bid >> 3, blk = bid & 7, tbase = tg * TGB;
  const __fp16* Wf = isA ? wiA : wiB;
  __fp16* preo = isA ? pre1o : pre2o;

  __shared__ __fp16 tiles[TGB][2048];   // 32KB, swizzled [16 node][128 k] per t

  if (isA){
    const int node = tid >> 4, k8 = tid & 15;
    const int gnode = blk * 16 + node;
    #pragma unroll
    for (int t = 0; t < TGB; t++){
      __fp16 tmp[8];
      if (gnode < NNODE){
        const float* s = x + ((size_t)gnode * TSEQ + (t0abs + tbase + t)) * 128 + k8 * 8;
        float4 a = ((const float4*)s)[0];
        float4 b = ((const float4*)s)[1];
        tmp[0]=(__fp16)a.x; tmp[1]=(__fp16)a.y; tmp[2]=(__fp16)a.z; tmp[3]=(__fp16)a.w;
        tmp[4]=(__fp16)b.x; tmp[5]=(__fp16)b.y; tmp[6]=(__fp16)b.z; tmp[7]=(__fp16)b.w;
      } else {
        #pragma unroll
        for (int i = 0; i < 8; i++) tmp[i] = (__fp16)0.f;
      }
      *(uint4*)((char*)&tiles[t][0] + swzb(node, k8 * 16)) = *(const uint4*)tmp;
    }
  } else {
    #pragma unroll
    for (int t = 0; t < TGB; t++){
      uint4 v = *(const uint4*)((const char*)ringr + (((size_t)(tbase + t) * 8 + blk) * 4096) + tid * 16);
      *(uint4*)((char*)&tiles[t][0] + tid * 16) = v;   // verbatim (already swizzled)
    }
  }

  // B-fragments: W rows, register-resident (64 VGPR)
  f16x8 WB[2][4][4];
  #pragma unroll
  for (int ws = 0; ws < 2; ws++)
    #pragma unroll
    for (int g = 0; g < 4; g++){
      const int gate = g * 128 + (w4 * 2 + ws) * 16 + l16;
      const __fp16* wp = Wf + (size_t)gate * 128 + q * 8;
      #pragma unroll
      for (int kt = 0; kt < 4; kt++) WB[ws][g][kt] = *(const f16x8*)(wp + kt * 32);
    }
  __syncthreads();

  #pragma unroll 1
  for (int t = 0; t < TGB; t++){
    f16x8 ax[4];
    #pragma unroll
    for (int kt = 0; kt < 4; kt++)
      ax[kt] = *(const f16x8*)((const char*)&tiles[t][0] + swzb(l16, kt * 64 + q * 16));
    #pragma unroll
    for (int ws = 0; ws < 2; ws++){
      const size_t off = ((((size_t)(tbase + t) * 8 + blk) * 8 + (size_t)(w4 * 2 + ws)) * 64 + (size_t)lane) * 32;
      #pragma unroll
      for (int g = 0; g < 4; g++){
        floatx4 acc = {0.f, 0.f, 0.f, 0.f};
        #pragma unroll
        for (int kt = 0; kt < 4; kt++)
          acc = __builtin_amdgcn_mfma_f32_16x16x32_f16(ax[kt], WB[ws][g][kt], acc, 0, 0, 0);
        __fp16 o[4];
        o[0]=(__fp16)acc[0]; o[1]=(__fp16)acc[1]; o[2]=(__fp16)acc[2]; o[3]=(__fp16)acc[3];
        *(uint2*)((char*)preo + off + g * 8) = *(const uint2*)o;
      }
    }
  }
}

// ---------------- recurrent-only MFMA scan ----------------
// 16 blocks x 512 thr (8 waves). Blocks 0..7: L1 chunk c; 8..15: L2 chunk c-1.
// Benched round-3 structure (plain __syncthreads, no asm) + two deltas:
//  (1) pre(t) acc-init loads are 32B contiguous/thread (2x dwordx4);
//  (2) h history kept in 16-deep LDS ring; L1 flushes 8 timesteps of ring
//      writes at once every 8 steps (opposite-half scheme), so the implicit
//      vmcnt(0) store-drain at __syncthreads is paid 32x/dispatch, not 256x.
__global__ __launch_bounds__(512, 2) void lstm_scan(
    const __fp16* __restrict__ pre1, const __fp16* __restrict__ pre2,
    __fp16* __restrict__ ring,
    const __fp16* __restrict__ whh0, const __fp16* __restrict__ whh1,
    const float* __restrict__ b_ih0, const float* __restrict__ b_hh0,
    const float* __restrict__ b_ih1, const float* __restrict__ b_hh1,
    __fp16* __restrict__ hs1, float* __restrict__ c1s,
    __fp16* __restrict__ hs2, float* __restrict__ c2s,
    float* __restrict__ pout, int c)
{
  const bool isL1 = blockIdx.x < 8;
  if (isL1){ if (c >= NCH) return; } else { if (c < 1) return; }
  const int blk = blockIdx.x & 7, n0 = blk * 16;
  const int tid = threadIdx.x, lane = tid & 63, w = tid >> 6;
  const int q = lane >> 4, l16 = lane & 15;

  __shared__ __fp16 hhist[16][2048];   // 64KB: swizzled h(t) tiles, mod-16 ring

  const __fp16* prebase = isL1 ? pre1 : pre2;
  const __fp16* Wh = isL1 ? whh0 : whh1;
  const float* bA = isL1 ? b_ih0 : b_ih1;
  const float* bB = isL1 ? b_hh0 : b_hh1;
  __fp16* hst = isL1 ? hs1 : hs2;
  float* cst = isL1 ? c1s : c2s;
  const bool zin = isL1 ? (c == 0) : (c == 1);
  char* ringw = (char*)(ring + (size_t)(c & 1) * TC * 8 * 2048);

  f16x8 WH[4][4];
  float bias[4];
  #pragma unroll
  for (int g = 0; g < 4; g++){
    const int gate = g * 128 + w * 16 + l16;
    const __fp16* wp = Wh + (size_t)gate * 128 + q * 8;
    #pragma unroll
    for (int kt = 0; kt < 4; kt++) WH[g][kt] = *(const f16x8*)(wp + kt * 32);
    bias[g] = bA[gate] + bB[gate];
  }

  float creg[4]; __fp16 hreg[4];
  #pragma unroll
  for (int r = 0; r < 4; r++){
    const int node = q * 4 + r, d = w * 16 + l16;
    __fp16 h0;
    if (zin){ creg[r] = 0.f; h0 = (__fp16)0.f; }
    else { creg[r] = cst[(size_t)(n0 + node) * 128 + d]; h0 = hst[(size_t)(n0 + node) * 128 + d]; }
    hreg[r] = h0;
    *(__fp16*)((char*)&hhist[15][0] + swzb(node, 2 * d)) = h0;   // h(-1) -> slot 15
  }

#define LDPRE(PR, T) do { \
    const char* _b = (const char*)prebase + ((((size_t)(T) * 8 + blk) * 8 + (size_t)w) * 64 + (size_t)lane) * 32; \
    PR[0] = ((const uint4*)_b)[0]; \
    PR[1] = ((const uint4*)_b)[1]; \
  } while (0)

#define STEP(P, CUR, NXT) do { \
    const char* hsrc = (const char*)&hhist[((P) + 15) & 15][0]; \
    if (isL1 && (P) >= 8 && (((P) & 7) == 0)){ \
      const int half_ = ((P) & 8) ? 0 : 8;      /* flush the OPPOSITE half */ \
      _Pragma("unroll") \
      for (int s_ = 0; s_ < 8; s_++){ \
        uint2 hv = *(const uint2*)((const char*)&hhist[half_ + s_][0] + tid * 8); \
        *(uint2*)(ringw + (((size_t)((P) - 8 + s_) * 8 + blk) * 4096) + tid * 8) = hv; \
      } \
    } \
    floatx4 acc[4]; \
    { \
      __fp16 pva[8], pvb[8]; \
      *(uint4*)pva = CUR[0]; *(uint4*)pvb = CUR[1]; \
      _Pragma("unroll") \
      for (int i_ = 0; i_ < 4; i_++){ \
        acc[0][i_] = (float)pva[i_];     acc[1][i_] = (float)pva[4 + i_]; \
        acc[2][i_] = (float)pvb[i_];     acc[3][i_] = (float)pvb[4 + i_]; \
      } \
    } \
    if ((P) + 1 < TC) LDPRE(NXT, (P) + 1); \
    f16x8 ah[4]; \
    _Pragma("unroll") \
    for (int kt = 0; kt < 4; kt++) \
      ah[kt] = *(const f16x8*)(hsrc + swzb(l16, kt * 64 + q * 16)); \
    _Pragma("unroll") \
    for (int kt = 0; kt < 4; kt++){ \
      _Pragma("unroll") \
      for (int g = 0; g < 4; g++) \
        acc[g] = __builtin_amdgcn_mfma_f32_16x16x32_f16(ah[kt], WH[g][kt], acc[g], 0, 0, 0); \
    } \
    char* hdst = (char*)&hhist[(P) & 15][0]; \
    _Pragma("unroll") \
    for (int r = 0; r < 4; r++){ \
      const float gi = acc[0][r] + bias[0]; \
      const float gf = acc[1][r] + bias[1]; \
      const float gc = acc[2][r] + bias[2]; \
      const float go = acc[3][r] + bias[3]; \
      float cc = sigm(gf) * creg[r] + sigm(gi) * tanhfast(gc); \
      creg[r] = cc; \
      const float h = sigm(go) * tanhfast(cc); \
      hreg[r] = (__fp16)h; \
      *(__fp16*)(hdst + swzb(q * 4 + r, 2 * (w * 16 + l16))) = hreg[r]; \
    } \
    __syncthreads(); \
  } while (0)

  uint4 prA[2], prB[2];
  LDPRE(prA, 0);
  __syncthreads();

  #pragma unroll 1
  for (int p = 0; p < TC; p += 2){
    STEP(p, prA, prB);
    STEP(p + 1, prB, prA);
  }

  // epilogue flush: steps TC-8..TC-1 live in slots 8..15 (TC % 16 == 0)
  if (isL1){
    #pragma unroll
    for (int s_ = 0; s_ < 8; s_++){
      uint2 hv = *(const uint2*)((const char*)&hhist[8 + s_][0] + tid * 8);
      *(uint2*)(ringw + (((size_t)(TC - 8 + s_) * 8 + blk) * 4096) + tid * 8) = hv;
    }
  }
  #pragma unroll
  for (int r = 0; r < 4; r++){
    const int node = q * 4 + r, d = w * 16 + l16;
    const size_t idx = (size_t)(n0 + node) * 128 + d;
    cst[idx] = creg[r];
    hst[idx] = hreg[r];
    if (!isL1 && c == NCH && (n0 + node) < NNODE) pout[idx] = leakyf((float)hreg[r]);
  }
#undef STEP
#undef LDPRE
}

// ---------------- H1: per-node MLP up to n ----------------
__global__ void node_mlp(
    const float* __restrict__ x_tag, const float* __restrict__ pm,
    const float* __restrict__ Wvm, const float* __restrict__ Wup,
    const float* __restrict__ W_hyb, const float* __restrict__ b_hyb,
    const float* __restrict__ W_act, const float* __restrict__ b_act,
    const float* __restrict__ W_inact, const float* __restrict__ b_inact,
    const float* __restrict__ p, float* __restrict__ nmat)
{
  int n = blockIdx.x, tid = threadIdx.x;
  __shared__ float pl[128], up[128], vm[128], hh[256];
  float act = x_tag[n * 3 + 2], hp0 = x_tag[n * 3 + 0], hp1 = x_tag[n * 3 + 1];
  if (tid < 128) pl[tid] = p[n * 128 + tid];
  __syncthreads();
  if (tid < 128){
    float a1 = 0.f;
    for (int k = 0; k < 768; k++) a1 += pm[k] * Wvm[k * 128 + tid];
    a1 += act * Wvm[768 * 128 + tid];
    vm[tid] = leakyf(a1);
    float a2 = 0.f;
    for (int k = 0; k < 128; k++) a2 += pl[k] * Wup[k * 128 + tid];
    up[tid] = leakyf(a2);
  }
  __syncthreads();
  {
    float a = b_hyb[tid];
    for (int k = 0; k < 128; k++) a += up[k] * W_hyb[k * 256 + tid];
    for (int k = 0; k < 128; k++) a += (up[k] + vm[k]) * W_hyb[(128 + k) * 256 + tid];
    for (int k = 0; k < 128; k++) a += vm[k] * W_hyb[(256 + k) * 256 + tid];
    hh[tid] = leakyf(a);
  }
  __syncthreads();
  {
    float na = b_act[tid];
    for (int k = 0; k < 256; k++) na += hh[k] * W_act[k * 256 + tid];
    na += hp0 * W_act[256 * 256 + tid] + hp1 * W_act[257 * 256 + tid];
    float ni = b_inact[tid];
    for (int k = 0; k < 256; k++) ni += hh[k] * W_inact[k * 256 + tid];
    nmat[n * 256 + tid] = leakyf(na * (1.f - act) + ni * act);
  }
}

// ---------------- H2: per-node projections of n ----------------
__global__ void node_proj(
    const float* __restrict__ nmat,
    const float* __restrict__ Wphin, const float* __restrict__ Won,
    const float* __restrict__ Weo,
    float* __restrict__ A, float* __restrict__ B,
    float* __restrict__ C, float* __restrict__ D,
    float* __restrict__ Q, float* __restrict__ R)
{
  int n = blockIdx.x, tid = threadIdx.x;
  __shared__ float nl[256];
  nl[tid] = nmat[n * 256 + tid];
  __syncthreads();
  if (tid < 192){
    float a = 0.f, b = 0.f;
    for (int k = 0; k < 256; k++){ float v = nl[k]; a += v * Wphin[k * 192 + tid]; b += v * Wphin[(256 + k) * 192 + tid]; }
    A[n * 192 + tid] = a; B[n * 192 + tid] = b;
  }
  float c = 0.f, d = 0.f, q = 0.f, r = 0.f;
  for (int k = 0; k < 256; k++){
    float v = nl[k];
    c += v * Won[k * 256 + tid];
    d += v * Won[(256 + k) * 256 + tid];
    q += v * Weo[(256 + k) * 256 + tid];
    r += v * Weo[(512 + k) * 256 + tid];
  }
  C[n * 256 + tid] = c; D[n * 256 + tid] = d;
  Q[n * 256 + tid] = q; R[n * 256 + tid] = r;
}

// ---------------- H3: phi ----------------
__global__ void phi_kernel(const float* __restrict__ A, const float* __restrict__ B,
                           const float* __restrict__ aphi, float* __restrict__ phiT)
{
  int j = blockIdx.x, tid = threadIdx.x;
  __shared__ float Aj[192], ap[192];
  for (int k = tid; k < 192; k += 128){ Aj[k] = A[j * 192 + k]; ap[k] = aphi[k]; }
  __syncthreads();
  if (tid < NNODE){
    const float* Bi = B + (size_t)tid * 192;
    float s = 0.f;
    for (int k = 0; k < 192; k++) s += leakyf(Aj[k] + Bi[k]) * ap[k];
    phiT[j * NNODE + tid] = s;
  }
}

// ---------------- H4: masked softmaxes ----------------
__global__ void alpha_kernel(const float* __restrict__ phiT, const float* __restrict__ x_tag,
                             float* __restrict__ alpha)
{
  int j = blockIdx.x, tid = threadIdx.x;
  __shared__ float buf[128];
  bool valid = tid < NNODE;
  float ph = valid ? phiT[j * NNODE + tid] : 0.f;
  float a  = valid ? x_tag[tid * 3 + 2] : -1.f;
  bool v1 = (a == 0.f), v0 = (a == 1.f);

  float c1 = bred_sum((valid && v1) ? 1.f : 0.f, buf, 128);

  float x1 = (valid && v1) ? ph : NEGC;
  float m1 = bred_max(valid ? x1 : -3.4e38f, buf, 128);
  float e1 = valid ? __expf(x1 - m1) : 0.f;
  float s1 = bred_sum(e1, buf, 128);
  float p1 = e1 / s1;

  float x0 = (valid && v0) ? ph : NEGC;
  float m0 = bred_max(valid ? x0 : -3.4e38f, buf, 128);
  float e0 = valid ? __expf(x0 - m0) : 0.f;
  float s0 = bred_sum(e0, buf, 128);
  float p0 = e0 / s0;

  float ma = bred_max(valid ? ph : -3.4e38f, buf, 128);
  float ea = valid ? __expf(ph - ma) : 0.f;
  float sa = bred_sum(ea, buf, 128);
  float pa = ea / sa;

  float pmask = v1 ? p1 : (v0 ? p0 : ph);
  float al = (c1 > 0.f) ? pmask : pa;
  if (valid) alpha[tid * NNODE + j] = al;
}

// ---------------- H5: alpha-weighted sums ----------------
__global__ void att_sum(const float* __restrict__ alpha, const float* __restrict__ C,
                        const float* __restrict__ D, const float* __restrict__ Q,
                        const float* __restrict__ R, const float* __restrict__ nmat,
                        float* __restrict__ T1, float* __restrict__ Spart,
                        float* __restrict__ nrm)
{
  int i = blockIdx.x, tid = threadIdx.x;
  __shared__ float al[128];
  __shared__ float rb[256];
  if (tid < 128) al[tid] = (tid < NNODE) ? alpha[i * NNODE + tid] : 0.f;
  __syncthreads();
  float Di = D[i * 256 + tid];
  float acc1 = 0.f, acc2 = 0.f, sa = 0.f;
  for (int jj = 0; jj < NNODE; jj++){
    float av = al[jj]; sa += av;
    acc1 += av * leakyf(C[jj * 256 + tid] + Di);
    acc2 += av * Q[jj * 256 + tid];
  }
  T1[i * 256 + tid] = acc1;
  Spart[i * 256 + tid] = acc2 + sa * R[i * 256 + tid];
  float nv = nmat[i * 256 + tid];
  float ss = bred_sum(nv * nv, rb, 256);
  if (tid == 0) nrm[i] = fmaxf(sqrtf(ss), 1e-8f);
}

// ---------------- H6: per-node finalize ----------------
__global__ void finalize_node(const float* __restrict__ T1, const float* __restrict__ Spart,
                              const float* __restrict__ Weo, const float* __restrict__ nmat,
                              const float* __restrict__ x_tag, const float* __restrict__ Wi,
                              const float* __restrict__ bi, const float* __restrict__ nrm,
                              float* __restrict__ vvec, float* __restrict__ out)
{
  int i = blockIdx.x, tid = threadIdx.x;
  __shared__ float t1[256];
  __shared__ float rb[256];
  t1[tid] = T1[i * 256 + tid];
  __syncthreads();
  float s = Spart[i * 256 + tid];
  for (int k = 0; k < 256; k++) s += t1[k] * Weo[k * 256 + tid];
  float act = x_tag[i * 3 + 2], hp0 = x_tag[i * 3 + 0], hp1 = x_tag[i * 3 + 1];
  float hm0 = leakyf(act * s);
  float hm1 = leakyf((1.f - act) * s);
  float nd = nmat[i * 256 + tid];
  const float* Wir = Wi + (size_t)i * 1536;
  float y0 = nd * Wir[tid * 2]     + hm0 * Wir[(256 + tid) * 2]     + hm1 * Wir[(512 + tid) * 2];
  float y1 = nd * Wir[tid * 2 + 1] + hm0 * Wir[(256 + tid) * 2 + 1] + hm1 * Wir[(512 + tid) * 2 + 1];
  y0 = bred_sum(y0, rb, 256);
  y1 = bred_sum(y1, rb, 256);
  float sgn = (hp1 > hp0) ? 1.f : ((hp1 < hp0) ? -1.f : 0.f);
  if (act == 0.f && sgn != 0.f) atomicAdd(vvec + tid, sgn * nd / nrm[i]);
  if (tid == 0){
    y0 += bi[i * 2]; y1 += bi[i * 2 + 1];
    float m = fmaxf(y0, y1);
    float ee0 = __expf(y0 - m), ee1 = __expf(y1 - m);
    float ssum = ee0 + ee1;
    out[i * 2]     = ee0 / ssum;
    out[i * 2 + 1] = ee1 / ssum;
    out[236 + i * 2]     = hp0;
    out[236 + i * 2 + 1] = hp1;
    out[474 + i] = (act == 0.f) ? 1.f : 0.f;
    out[592 + i] = (act == 1.f) ? 1.f : 0.f;
  }
}

// ---------------- H_ort ----------------
__global__ void ort_kernel(const float* __restrict__ Wum, const float* __restrict__ Wvm,
                           const float* __restrict__ Wup, const float* __restrict__ Wvp,
                           float* __restrict__ misc)
{
  int a = blockIdx.x, b = threadIdx.x;
  float g1 = 0.f, g2 = 0.f, g3 = 0.f, g4 = 0.f;
  for (int r = 0; r < 769; r++){
    g1 += Wum[r * 128 + a] * Wum[r * 128 + b];
    g2 += Wvm[r * 128 + a] * Wvm[r * 128 + b];
  }
  for (int r = 0; r < 128; r++){
    g3 += Wup[r * 128 + a] * Wup[r * 128 + b];
    g4 += Wvp[r * 128 + a] * Wvp[r * 128 + b];
  }
  __shared__ float rb[128];
  float s1 = bred_sum(g1 * g2, rb, 128);
  float s2 = bred_sum(g3 * g4, rb, 128);
  if (b == 0){ atomicAdd(misc + 0, s1); atomicAdd(misc + 1, s2); }
}

// ---------------- H7: scalars ----------------
__global__ void finalize_scalars(const float* __restrict__ misc, const float* __restrict__ vvec,
                                 float* __restrict__ out)
{
  __shared__ float rb[256];
  int tid = threadIdx.x;
  float v = vvec[tid];
  float ss = bred_sum(v * v, rb, 256);
  if (tid == 0){
    out[472] = sqrtf(misc[0]) + sqrtf(misc[1]);
    out[473] = ss;
  }
}

extern "C" void kernel_launch(void* const* d_in, const int* in_sizes, int n_in,
                              void* d_out, int out_size, void* d_ws, size_t ws_size,
                              hipStream_t stream)
{
  const float* x        = (const float*)d_in[0];
  const float* x_tag    = (const float*)d_in[1];
  const float* W_ih0    = (const float*)d_in[2];
  const float* W_hh0    = (const float*)d_in[3];
  const float* b_ih0    = (const float*)d_in[4];
  const float* b_hh0    = (const float*)d_in[5];
  const float* W_ih1    = (const float*)d_in[6];
  const float* W_hh1    = (const float*)d_in[7];
  const float* b_ih1    = (const float*)d_in[8];
  const float* b_hh1    = (const float*)d_in[9];
  const float* pm       = (const float*)d_in[10];
  const float* Wum      = (const float*)d_in[11];
  const float* Wvm      = (const float*)d_in[12];
  const float* Wup      = (const float*)d_in[13];
  const float* Wvp      = (const float*)d_in[14];
  const float* W_hyb    = (const float*)d_in[15];
  const float* b_hyb    = (const float*)d_in[16];
  const float* W_act    = (const float*)d_in[17];
  const float* b_act    = (const float*)d_in[18];
  const float* W_inact  = (const float*)d_in[19];
  const float* b_inact  = (const float*)d_in[20];
  const float* Wphin    = (const float*)d_in[21];
  const float* aphi     = (const float*)d_in[22];
  const float* Won      = (const float*)d_in[23];
  const float* Weo      = (const float*)d_in[24];
  const float* Wi       = (const float*)d_in[25];
  const float* bi       = (const float*)d_in[26];
  float* out = (float*)d_out;

  char* base = (char*)d_ws;
  size_t off = 0;
  auto take = [&](size_t bytes) -> char* {
    char* p = base + off;
    off += (bytes + 255) & ~(size_t)255;
    return p;
  };
  __fp16* pre1   = (__fp16*)take((size_t)TC * 8 * 32 * 512);           // 32MB
  __fp16* pre2   = (__fp16*)take((size_t)TC * 8 * 32 * 512);           // 32MB
  __fp16* h1ring = (__fp16*)take((size_t)2 * TC * 8 * 2048 * 2);       // 16MB
  __fp16* wih0h  = (__fp16*)take((size_t)512 * 128 * 2);
  __fp16* wih1h  = (__fp16*)take((size_t)512 * 128 * 2);
  __fp16* whh0h  = (__fp16*)take((size_t)512 * 128 * 2);
  __fp16* whh1h  = (__fp16*)take((size_t)512 * 128 * 2);
  __fp16* hs1    = (__fp16*)take((size_t)128 * 128 * 2);
  float* c1s     = (float*)take((size_t)128 * 128 * 4);
  __fp16* hs2    = (__fp16*)take((size_t)128 * 128 * 2);
  float* c2s     = (float*)take((size_t)128 * 128 * 4);
  float* pbuf  = (float*)take((size_t)NNODE * 128 * 4);
  float* nmat  = (float*)take((size_t)NNODE * 256 * 4);
  float* Amat  = (float*)take((size_t)NNODE * 192 * 4);
  float* Bmat  = (float*)take((size_t)NNODE * 192 * 4);
  float* Cmat  = (float*)take((size_t)NNODE * 256 * 4);
  float* Dmat  = (float*)take((size_t)NNODE * 256 * 4);
  float* Qmat  = (float*)take((size_t)NNODE * 256 * 4);
  float* Rmat  = (float*)take((size_t)NNODE * 256 * 4);
  float* phiT  = (float*)take((size_t)NNODE * NNODE * 4);
  float* alpha = (float*)take((size_t)NNODE * NNODE * 4);
  float* T1    = (float*)take((size_t)NNODE * 256 * 4);
  float* Spart = (float*)take((size_t)NNODE * 256 * 4);
  float* nrm   = (float*)take((size_t)NNODE * 4);
  float* vvec  = (float*)take(256 * 4);
  float* misc  = (float*)take(8 * 4);

  hipMemsetAsync(vvec, 0, 1024 + 32, stream);

  f32_to_f16_k<<<256, 256, 0, stream>>>(W_ih0, wih0h, 512 * 128);
  f32_to_f16_k<<<256, 256, 0, stream>>>(W_ih1, wih1h, 512 * 128);
  f32_to_f16_k<<<256, 256, 0, stream>>>(W_hh0, whh0h, 512 * 128);
  f32_to_f16_k<<<256, 256, 0, stream>>>(W_hh1, whh1h, 512 * 128);

  const size_t ringslot = (size_t)TC * 8 * 2048;   // f16 units
  const int gpb = (TC / TGB) * 8;                  // 256 blocks per projection
  for (int c = 0; c <= NCH; c++){
    const int n1 = (c < NCH) ? gpb : 0;
    const int n2 = (c >= 1) ? gpb : 0;
    if (n1 + n2 > 0)
      gateproj<<<n1 + n2, 256, 0, stream>>>(x, h1ring + (size_t)((c - 1) & 1) * ringslot,
                                            wih0h, wih1h, pre1, pre2, n1, c * TC);
    lstm_scan<<<16, 512, 0, stream>>>(pre1, pre2, h1ring, whh0h, whh1h,
                                      b_ih0, b_hh0, b_ih1, b_hh1,
                                      hs1, c1s, hs2, c2s, pbuf, c);
  }

  node_mlp<<<NNODE, 256, 0, stream>>>(x_tag, pm, Wvm, Wup, W_hyb, b_hyb,
                                      W_act, b_act, W_inact, b_inact, pbuf, nmat);
  node_proj<<<NNODE, 256, 0, stream>>>(nmat, Wphin, Won, Weo, Amat, Bmat, Cmat, Dmat, Qmat, Rmat);
  phi_kernel<<<NNODE, 128, 0, stream>>>(Amat, Bmat, aphi, phiT);
  alpha_kernel<<<NNODE, 128, 0, stream>>>(phiT, x_tag, alpha);
  att_sum<<<NNODE, 256, 0, stream>>>(alpha, Cmat, Dmat, Qmat, Rmat, nmat, T1, Spart, nrm);
  finalize_node<<<NNODE, 256, 0, stream>>>(T1, Spart, Weo, nmat, x_tag, Wi, bi, nrm, vvec, out);
  ort_kernel<<<128, 128, 0, stream>>>(Wum, Wvm, Wup, Wvp, misc);
  finalize_scalars<<<1, 256, 0, stream>>>(misc, vvec, out);
}

// Round 8
// 2953.475 us; speedup vs baseline: 1.1342x; 1.1342x over previous
//
#include <hip/hip_runtime.h>
#include <cstdint>
#include <cstddef>

#define NNODE 118
#define TSEQ  2048
#define TC    256         // chunk length
#define NCH   8
#define TGB   8           // timesteps per gateproj block
#define NEGC  -1000000000.0f

typedef __fp16 f16x8 __attribute__((ext_vector_type(8)));
typedef float floatx4 __attribute__((ext_vector_type(4)));

__device__ __forceinline__ float leakyf(float x){ return x >= 0.f ? x : 0.01f * x; }
__device__ __forceinline__ float frcp(float x){ return __builtin_amdgcn_rcpf(x); }
__device__ __forceinline__ float sigm(float x){ return frcp(1.f + __expf(-x)); }
__device__ __forceinline__ float tanhfast(float x){ return 1.f - 2.f * frcp(__expf(2.f * x) + 1.f); }

// byte offset of (row, colByte) in a 16x256B tile; XOR swizzle spreads the 16
// rows across distinct 16B/32B bank groups (2B scatter writes -> 2 lanes/bank).
__device__ __forceinline__ int swzb(int row, int colByte){
  return row * 256 + (colByte ^ ((row & 7) << 4) ^ ((row & 8) << 2));
}

__device__ float bred_sum(float v, float* buf, int nthr){
  int tid = threadIdx.x;
  buf[tid] = v; __syncthreads();
  for (int s = nthr >> 1; s > 0; s >>= 1){
    if (tid < s) buf[tid] += buf[tid + s];
    __syncthreads();
  }
  float r = buf[0]; __syncthreads(); return r;
}
__device__ float bred_max(float v, float* buf, int nthr){
  int tid = threadIdx.x;
  buf[tid] = v; __syncthreads();
  for (int s = nthr >> 1; s > 0; s >>= 1){
    if (tid < s) buf[tid] = fmaxf(buf[tid], buf[tid + s]);
    __syncthreads();
  }
  float r = buf[0]; __syncthreads(); return r;
}

// ---------------- converts ----------------
__global__ void f32_to_f16_k(const float* __restrict__ in, __fp16* __restrict__ out, int n){
  int i = blockIdx.x * blockDim.x + threadIdx.x;
  if (i < n) out[i] = (__fp16)in[i];
}

// ---------------- gate projection (parallel over t) ----------------
// Blocks [0, n1): pre1[t] = x(t) @ W_ih0^T + bias0  (reads f32 x)
// Blocks [n1,..): pre2[t] = h1(t) @ W_ih1^T + bias1 (reads swizzled f16 ring)
// Bias is folded here (amortized in the parallel kernel) so the serial scan
// drops 16 adds/thread/step. Output layout [t][blk][wave][lane][4 x 8B].
__global__ __launch_bounds__(256, 2) void gateproj(
    const float* __restrict__ x,
    const __fp16* __restrict__ ringr,
    const __fp16* __restrict__ wiA,      // W_ih0 f16 [512][128]
    const __fp16* __restrict__ wiB,      // W_ih1 f16 [512][128]
    const float* __restrict__ bA_ih, const float* __restrict__ bA_hh,
    const float* __restrict__ bB_ih, const float* __restrict__ bB_hh,
    __fp16* __restrict__ pre1o, __fp16* __restrict__ pre2o,
    int n1blocks, int t0abs)
{
  const int tid = threadIdx.x, lane = tid & 63, w4 = tid >> 6;
  const int q = lane >> 4, l16 = lane & 15;
  const bool isA = (int)blockIdx.x < n1blocks;
  const int bid = isA ? blockIdx.x : (blockIdx.x - n1blocks);
  const int tg = bid >> 3, blk = bid & 7, tbase = tg * TGB;
  const __fp16* Wf = isA ? wiA : wiB;
  const float* bih = isA ? bA_ih : bB_ih;
  const float* bhh = isA ? bA_hh : bB_hh;
  __fp16* preo = isA ? pre1o : pre2o;

  __shared__ __fp16 tiles[TGB][2048];   // 32KB, swizzled [16 node][128 k] per t

  if (isA){
    const int node = tid >> 4, k8 = tid & 15;
    const int gnode = blk * 16 + node;
    #pragma unroll
    for (int t = 0; t < TGB; t++){
      __fp16 tmp[8];
      if (gnode < NNODE){
        const float* s = x + ((size_t)gnode * TSEQ + (t0abs + tbase + t)) * 128 + k8 * 8;
        float4 a = ((const float4*)s)[0];
        float4 b = ((const float4*)s)[1];
        tmp[0]=(__fp16)a.x; tmp[1]=(__fp16)a.y; tmp[2]=(__fp16)a.z; tmp[3]=(__fp16)a.w;
        tmp[4]=(__fp16)b.x; tmp[5]=(__fp16)b.y; tmp[6]=(__fp16)b.z; tmp[7]=(__fp16)b.w;
      } else {
        #pragma unroll
        for (int i = 0; i < 8; i++) tmp[i] = (__fp16)0.f;
      }
      *(uint4*)((char*)&tiles[t][0] + swzb(node, k8 * 16)) = *(const uint4*)tmp;
    }
  } else {
    #pragma unroll
    for (int t = 0; t < TGB; t++){
      uint4 v = *(const uint4*)((const char*)ringr + (((size_t)(tbase + t) * 8 + blk) * 4096) + tid * 16);
      *(uint4*)((char*)&tiles[t][0] + tid * 16) = v;   // verbatim (already swizzled)
    }
  }

  // B-fragments: W rows + folded bias, register-resident
  f16x8 WB[2][4][4];
  float bsum[2][4];
  #pragma unroll
  for (int ws = 0; ws < 2; ws++)
    #pragma unroll
    for (int g = 0; g < 4; g++){
      const int gate = g * 128 + (w4 * 2 + ws) * 16 + l16;
      const __fp16* wp = Wf + (size_t)gate * 128 + q * 8;
      #pragma unroll
      for (int kt = 0; kt < 4; kt++) WB[ws][g][kt] = *(const f16x8*)(wp + kt * 32);
      bsum[ws][g] = bih[gate] + bhh[gate];
    }
  __syncthreads();

  #pragma unroll 1
  for (int t = 0; t < TGB; t++){
    f16x8 ax[4];
    #pragma unroll
    for (int kt = 0; kt < 4; kt++)
      ax[kt] = *(const f16x8*)((const char*)&tiles[t][0] + swzb(l16, kt * 64 + q * 16));
    #pragma unroll
    for (int ws = 0; ws < 2; ws++){
      const size_t off = ((((size_t)(tbase + t) * 8 + blk) * 8 + (size_t)(w4 * 2 + ws)) * 64 + (size_t)lane) * 32;
      #pragma unroll
      for (int g = 0; g < 4; g++){
        floatx4 acc = {0.f, 0.f, 0.f, 0.f};
        #pragma unroll
        for (int kt = 0; kt < 4; kt++)
          acc = __builtin_amdgcn_mfma_f32_16x16x32_f16(ax[kt], WB[ws][g][kt], acc, 0, 0, 0);
        __fp16 o[4];
        const float bb = bsum[ws][g];
        o[0]=(__fp16)(acc[0]+bb); o[1]=(__fp16)(acc[1]+bb);
        o[2]=(__fp16)(acc[2]+bb); o[3]=(__fp16)(acc[3]+bb);
        *(uint2*)((char*)preo + off + g * 8) = *(const uint2*)o;
      }
    }
  }
}

// ---------------- recurrent-only MFMA scan ----------------
// 16 blocks x 512 thr (8 waves). Blocks 0..7: L1 chunk c; 8..15: L2 chunk c-1.
// Round-7 base + this round's experiment:
//  (a) counted barrier in the step loop: lgkmcnt(0)-only (no vmcnt drain) so
//      the 2-step-deep pre prefetch and ring stores stay in flight (T4);
//  (b) bias pre-folded in gateproj; fused-reciprocal nonlinearity (10->7
//      transcendentals per h, algebraically identical).
__global__ __launch_bounds__(512, 2) void lstm_scan(
    const __fp16* __restrict__ pre1, const __fp16* __restrict__ pre2,
    __fp16* __restrict__ ring,
    const __fp16* __restrict__ whh0, const __fp16* __restrict__ whh1,
    __fp16* __restrict__ hs1, float* __restrict__ c1s,
    __fp16* __restrict__ hs2, float* __restrict__ c2s,
    float* __restrict__ pout, int c)
{
  const bool isL1 = blockIdx.x < 8;
  if (isL1){ if (c >= NCH) return; } else { if (c < 1) return; }
  const int blk = blockIdx.x & 7, n0 = blk * 16;
  const int tid = threadIdx.x, lane = tid & 63, w = tid >> 6;
  const int q = lane >> 4, l16 = lane & 15;

  __shared__ __fp16 hhist[16][2048];   // 64KB: swizzled h(t) tiles, mod-16 ring

  const __fp16* prebase = isL1 ? pre1 : pre2;
  const __fp16* Wh = isL1 ? whh0 : whh1;
  __fp16* hst = isL1 ? hs1 : hs2;
  float* cst = isL1 ? c1s : c2s;
  const bool zin = isL1 ? (c == 0) : (c == 1);
  char* ringw = (char*)(ring + (size_t)(c & 1) * TC * 8 * 2048);

  f16x8 WH[4][4];
  #pragma unroll
  for (int g = 0; g < 4; g++){
    const int gate = g * 128 + w * 16 + l16;
    const __fp16* wp = Wh + (size_t)gate * 128 + q * 8;
    #pragma unroll
    for (int kt = 0; kt < 4; kt++) WH[g][kt] = *(const f16x8*)(wp + kt * 32);
  }

  float creg[4]; __fp16 hreg[4];
  #pragma unroll
  for (int r = 0; r < 4; r++){
    const int node = q * 4 + r, d = w * 16 + l16;
    __fp16 h0;
    if (zin){ creg[r] = 0.f; h0 = (__fp16)0.f; }
    else { creg[r] = cst[(size_t)(n0 + node) * 128 + d]; h0 = hst[(size_t)(n0 + node) * 128 + d]; }
    hreg[r] = h0;
    *(__fp16*)((char*)&hhist[15][0] + swzb(node, 2 * d)) = h0;   // h(-1) -> slot 15
  }

#define LDPRE(PR, T) do { \
    const char* _b = (const char*)prebase + ((((size_t)(T) * 8 + blk) * 8 + (size_t)w) * 64 + (size_t)lane) * 32; \
    PR[0] = ((const uint4*)_b)[0]; \
    PR[1] = ((const uint4*)_b)[1]; \
  } while (0)

// counted barrier: LDS handoff ordered via lgkmcnt(0); vmcnt NOT drained, so
// the 2-deep pre prefetch and ring stores stay in flight across steps.
#define SYNC() do { \
    __builtin_amdgcn_sched_barrier(0); \
    asm volatile("s_waitcnt lgkmcnt(0)"); \
    __builtin_amdgcn_sched_barrier(0); \
    __builtin_amdgcn_s_barrier(); \
  } while (0)

#define STEP(P, CUR) do { \
    const char* hsrc = (const char*)&hhist[((P) + 15) & 15][0]; \
    if (isL1 && (P) >= 8 && (((P) & 7) == 0)){ \
      const int half_ = ((P) & 8) ? 0 : 8;      /* flush the OPPOSITE half */ \
      _Pragma("unroll") \
      for (int s_ = 0; s_ < 8; s_++){ \
        uint2 hv = *(const uint2*)((const char*)&hhist[half_ + s_][0] + tid * 8); \
        *(uint2*)(ringw + (((size_t)((P) - 8 + s_) * 8 + blk) * 4096) + tid * 8) = hv; \
      } \
    } \
    floatx4 acc[4]; \
    { \
      __fp16 pva[8], pvb[8]; \
      *(uint4*)pva = CUR[0]; *(uint4*)pvb = CUR[1]; \
      _Pragma("unroll") \
      for (int i_ = 0; i_ < 4; i_++){ \
        acc[0][i_] = (float)pva[i_];     acc[1][i_] = (float)pva[4 + i_]; \
        acc[2][i_] = (float)pvb[i_];     acc[3][i_] = (float)pvb[4 + i_]; \
      } \
    } \
    if ((P) + 2 < TC) LDPRE(CUR, (P) + 2); \
    f16x8 ah[4]; \
    _Pragma("unroll") \
    for (int kt = 0; kt < 4; kt++) \
      ah[kt] = *(const f16x8*)(hsrc + swzb(l16, kt * 64 + q * 16)); \
    _Pragma("unroll") \
    for (int kt = 0; kt < 4; kt++){ \
      _Pragma("unroll") \
      for (int g = 0; g < 4; g++) \
        acc[g] = __builtin_amdgcn_mfma_f32_16x16x32_f16(ah[kt], WH[g][kt], acc[g], 0, 0, 0); \
    } \
    char* hdst = (char*)&hhist[(P) & 15][0]; \
    _Pragma("unroll") \
    for (int r = 0; r < 4; r++){ \
      /* fused-rcp LSTM cell: c' = c/A + (G-2)/(B*G); h = (T-2)/(T*D) */ \
      const float A_ = 1.f + __expf(-acc[1][r]);          /* 1+e^{-gf} */ \
      const float B_ = 1.f + __expf(-acc[0][r]);          /* 1+e^{-gi} */ \
      const float G_ = __expf(2.f * acc[2][r]) + 1.f;     /* e^{2gg}+1 */ \
      const float BG_ = B_ * G_; \
      const float num_ = creg[r] * BG_ + A_ * (G_ - 2.f); \
      const float cc = num_ * frcp(A_ * BG_); \
      creg[r] = cc; \
      const float T_ = __expf(2.f * cc) + 1.f; \
      const float D_ = 1.f + __expf(-acc[3][r]);          /* 1+e^{-go} */ \
      const float h = (T_ - 2.f) * frcp(T_ * D_); \
      hreg[r] = (__fp16)h; \
      *(__fp16*)(hdst + swzb(q * 4 + r, 2 * (w * 16 + l16))) = hreg[r]; \
    } \
    SYNC(); \
  } while (0)

  uint4 prA[2], prB[2];
  LDPRE(prA, 0);
  LDPRE(prB, 1);
  __syncthreads();

  #pragma unroll 1
  for (int p = 0; p < TC; p += 2){
    STEP(p, prA);
    STEP(p + 1, prB);
  }

  // epilogue flush: steps TC-8..TC-1 live in slots 8..15 (TC % 16 == 0)
  if (isL1){
    #pragma unroll
    for (int s_ = 0; s_ < 8; s_++){
      uint2 hv = *(const uint2*)((const char*)&hhist[8 + s_][0] + tid * 8);
      *(uint2*)(ringw + (((size_t)(TC - 8 + s_) * 8 + blk) * 4096) + tid * 8) = hv;
    }
  }
  #pragma unroll
  for (int r = 0; r < 4; r++){
    const int node = q * 4 + r, d = w * 16 + l16;
    const size_t idx = (size_t)(n0 + node) * 128 + d;
    cst[idx] = creg[r];
    hst[idx] = hreg[r];
    if (!isL1 && c == NCH && (n0 + node) < NNODE) pout[idx] = leakyf((float)hreg[r]);
  }
#undef STEP
#undef SYNC
#undef LDPRE
}

// ---------------- H1: per-node MLP up to n ----------------
__global__ void node_mlp(
    const float* __restrict__ x_tag, const float* __restrict__ pm,
    const float* __restrict__ Wvm, const float* __restrict__ Wup,
    const float* __restrict__ W_hyb, const float* __restrict__ b_hyb,
    const float* __restrict__ W_act, const float* __restrict__ b_act,
    const float* __restrict__ W_inact, const float* __restrict__ b_inact,
    const float* __restrict__ p, float* __restrict__ nmat)
{
  int n = blockIdx.x, tid = threadIdx.x;
  __shared__ float pl[128], up[128], vm[128], hh[256];
  float act = x_tag[n * 3 + 2], hp0 = x_tag[n * 3 + 0], hp1 = x_tag[n * 3 + 1];
  if (tid < 128) pl[tid] = p[n * 128 + tid];
  __syncthreads();
  if (tid < 128){
    float a1 = 0.f;
    for (int k = 0; k < 768; k++) a1 += pm[k] * Wvm[k * 128 + tid];
    a1 += act * Wvm[768 * 128 + tid];
    vm[tid] = leakyf(a1);
    float a2 = 0.f;
    for (int k = 0; k < 128; k++) a2 += pl[k] * Wup[k * 128 + tid];
    up[tid] = leakyf(a2);
  }
  __syncthreads();
  {
    float a = b_hyb[tid];
    for (int k = 0; k < 128; k++) a += up[k] * W_hyb[k * 256 + tid];
    for (int k = 0; k < 128; k++) a += (up[k] + vm[k]) * W_hyb[(128 + k) * 256 + tid];
    for (int k = 0; k < 128; k++) a += vm[k] * W_hyb[(256 + k) * 256 + tid];
    hh[tid] = leakyf(a);
  }
  __syncthreads();
  {
    float na = b_act[tid];
    for (int k = 0; k < 256; k++) na += hh[k] * W_act[k * 256 + tid];
    na += hp0 * W_act[256 * 256 + tid] + hp1 * W_act[257 * 256 + tid];
    float ni = b_inact[tid];
    for (int k = 0; k < 256; k++) ni += hh[k] * W_inact[k * 256 + tid];
    nmat[n * 256 + tid] = leakyf(na * (1.f - act) + ni * act);
  }
}

// ---------------- H2: per-node projections of n ----------------
__global__ void node_proj(
    const float* __restrict__ nmat,
    const float* __restrict__ Wphin, const float* __restrict__ Won,
    const float* __restrict__ Weo,
    float* __restrict__ A, float* __restrict__ B,
    float* __restrict__ C, float* __restrict__ D,
    float* __restrict__ Q, float* __restrict__ R)
{
  int n = blockIdx.x, tid = threadIdx.x;
  __shared__ float nl[256];
  nl[tid] = nmat[n * 256 + tid];
  __syncthreads();
  if (tid < 192){
    float a = 0.f, b = 0.f;
    for (int k = 0; k < 256; k++){ float v = nl[k]; a += v * Wphin[k * 192 + tid]; b += v * Wphin[(256 + k) * 192 + tid]; }
    A[n * 192 + tid] = a; B[n * 192 + tid] = b;
  }
  float c = 0.f, d = 0.f, q = 0.f, r = 0.f;
  for (int k = 0; k < 256; k++){
    float v = nl[k];
    c += v * Won[k * 256 + tid];
    d += v * Won[(256 + k) * 256 + tid];
    q += v * Weo[(256 + k) * 256 + tid];
    r += v * Weo[(512 + k) * 256 + tid];
  }
  C[n * 256 + tid] = c; D[n * 256 + tid] = d;
  Q[n * 256 + tid] = q; R[n * 256 + tid] = r;
}

// ---------------- H3: phi ----------------
__global__ void phi_kernel(const float* __restrict__ A, const float* __restrict__ B,
                           const float* __restrict__ aphi, float* __restrict__ phiT)
{
  int j = blockIdx.x, tid = threadIdx.x;
  __shared__ float Aj[192], ap[192];
  for (int k = tid; k < 192; k += 128){ Aj[k] = A[j * 192 + k]; ap[k] = aphi[k]; }
  __syncthreads();
  if (tid < NNODE){
    const float* Bi = B + (size_t)tid * 192;
    float s = 0.f;
    for (int k = 0; k < 192; k++) s += leakyf(Aj[k] + Bi[k]) * ap[k];
    phiT[j * NNODE + tid] = s;
  }
}

// ---------------- H4: masked softmaxes ----------------
__global__ void alpha_kernel(const float* __restrict__ phiT, const float* __restrict__ x_tag,
                             float* __restrict__ alpha)
{
  int j = blockIdx.x, tid = threadIdx.x;
  __shared__ float buf[128];
  bool valid = tid < NNODE;
  float ph = valid ? phiT[j * NNODE + tid] : 0.f;
  float a  = valid ? x_tag[tid * 3 + 2] : -1.f;
  bool v1 = (a == 0.f), v0 = (a == 1.f);

  float c1 = bred_sum((valid && v1) ? 1.f : 0.f, buf, 128);

  float x1 = (valid && v1) ? ph : NEGC;
  float m1 = bred_max(valid ? x1 : -3.4e38f, buf, 128);
  float e1 = valid ? __expf(x1 - m1) : 0.f;
  float s1 = bred_sum(e1, buf, 128);
  float p1 = e1 / s1;

  float x0 = (valid && v0) ? ph : NEGC;
  float m0 = bred_max(valid ? x0 : -3.4e38f, buf, 128);
  float e0 = valid ? __expf(x0 - m0) : 0.f;
  float s0 = bred_sum(e0, buf, 128);
  float p0 = e0 / s0;

  float ma = bred_max(valid ? ph : -3.4e38f, buf, 128);
  float ea = valid ? __expf(ph - ma) : 0.f;
  float sa = bred_sum(ea, buf, 128);
  float pa = ea / sa;

  float pmask = v1 ? p1 : (v0 ? p0 : ph);
  float al = (c1 > 0.f) ? pmask : pa;
  if (valid) alpha[tid * NNODE + j] = al;
}

// ---------------- H5: alpha-weighted sums ----------------
__global__ void att_sum(const float* __restrict__ alpha, const float* __restrict__ C,
                        const float* __restrict__ D, const float* __restrict__ Q,
                        const float* __restrict__ R, const float* __restrict__ nmat,
                        float* __restrict__ T1, float* __restrict__ Spart,
                        float* __restrict__ nrm)
{
  int i = blockIdx.x, tid = threadIdx.x;
  __shared__ float al[128];
  __shared__ float rb[256];
  if (tid < 128) al[tid] = (tid < NNODE) ? alpha[i * NNODE + tid] : 0.f;
  __syncthreads();
  float Di = D[i * 256 + tid];
  float acc1 = 0.f, acc2 = 0.f, sa = 0.f;
  for (int jj = 0; jj < NNODE; jj++){
    float av = al[jj]; sa += av;
    acc1 += av * leakyf(C[jj * 256 + tid] + Di);
    acc2 += av * Q[jj * 256 + tid];
  }
  T1[i * 256 + tid] = acc1;
  Spart[i * 256 + tid] = acc2 + sa * R[i * 256 + tid];
  float nv = nmat[i * 256 + tid];
  float ss = bred_sum(nv * nv, rb, 256);
  if (tid == 0) nrm[i] = fmaxf(sqrtf(ss), 1e-8f);
}

// ---------------- H6: per-node finalize ----------------
__global__ void finalize_node(const float* __restrict__ T1, const float* __restrict__ Spart,
                              const float* __restrict__ Weo, const float* __restrict__ nmat,
                              const float* __restrict__ x_tag, const float* __restrict__ Wi,
                              const float* __restrict__ bi, const float* __restrict__ nrm,
                              float* __restrict__ vvec, float* __restrict__ out)
{
  int i = blockIdx.x, tid = threadIdx.x;
  __shared__ float t1[256];
  __shared__ float rb[256];
  t1[tid] = T1[i * 256 + tid];
  __syncthreads();
  float s = Spart[i * 256 + tid];
  for (int k = 0; k < 256; k++) s += t1[k] * Weo[k * 256 + tid];
  float act = x_tag[i * 3 + 2], hp0 = x_tag[i * 3 + 0], hp1 = x_tag[i * 3 + 1];
  float hm0 = leakyf(act * s);
  float hm1 = leakyf((1.f - act) * s);
  float nd = nmat[i * 256 + tid];
  const float* Wir = Wi + (size_t)i * 1536;
  float y0 = nd * Wir[tid * 2]     + hm0 * Wir[(256 + tid) * 2]     + hm1 * Wir[(512 + tid) * 2];
  float y1 = nd * Wir[tid * 2 + 1] + hm0 * Wir[(256 + tid) * 2 + 1] + hm1 * Wir[(512 + tid) * 2 + 1];
  y0 = bred_sum(y0, rb, 256);
  y1 = bred_sum(y1, rb, 256);
  float sgn = (hp1 > hp0) ? 1.f : ((hp1 < hp0) ? -1.f : 0.f);
  if (act == 0.f && sgn != 0.f) atomicAdd(vvec + tid, sgn * nd / nrm[i]);
  if (tid == 0){
    y0 += bi[i * 2]; y1 += bi[i * 2 + 1];
    float m = fmaxf(y0, y1);
    float ee0 = __expf(y0 - m), ee1 = __expf(y1 - m);
    float ssum = ee0 + ee1;
    out[i * 2]     = ee0 / ssum;
    out[i * 2 + 1] = ee1 / ssum;
    out[236 + i * 2]     = hp0;
    out[236 + i * 2 + 1] = hp1;
    out[474 + i] = (act == 0.f) ? 1.f : 0.f;
    out[592 + i] = (act == 1.f) ? 1.f : 0.f;
  }
}

// ---------------- H_ort ----------------
__global__ void ort_kernel(const float* __restrict__ Wum, const float* __restrict__ Wvm,
                           const float* __restrict__ Wup, const float* __restrict__ Wvp,
                           float* __restrict__ misc)
{
  int a = blockIdx.x, b = threadIdx.x;
  float g1 = 0.f, g2 = 0.f, g3 = 0.f, g4 = 0.f;
  for (int r = 0; r < 769; r++){
    g1 += Wum[r * 128 + a] * Wum[r * 128 + b];
    g2 += Wvm[r * 128 + a] * Wvm[r * 128 + b];
  }
  for (int r = 0; r < 128; r++){
    g3 += Wup[r * 128 + a] * Wup[r * 128 + b];
    g4 += Wvp[r * 128 + a] * Wvp[r * 128 + b];
  }
  __shared__ float rb[128];
  float s1 = bred_sum(g1 * g2, rb, 128);
  float s2 = bred_sum(g3 * g4, rb, 128);
  if (b == 0){ atomicAdd(misc + 0, s1); atomicAdd(misc + 1, s2); }
}

// ---------------- H7: scalars ----------------
__global__ void finalize_scalars(const float* __restrict__ misc, const float* __restrict__ vvec,
                                 float* __restrict__ out)
{
  __shared__ float rb[256];
  int tid = threadIdx.x;
  float v = vvec[tid];
  float ss = bred_sum(v * v, rb, 256);
  if (tid == 0){
    out[472] = sqrtf(misc[0]) + sqrtf(misc[1]);
    out[473] = ss;
  }
}

extern "C" void kernel_launch(void* const* d_in, const int* in_sizes, int n_in,
                              void* d_out, int out_size, void* d_ws, size_t ws_size,
                              hipStream_t stream)
{
  const float* x        = (const float*)d_in[0];
  const float* x_tag    = (const float*)d_in[1];
  const float* W_ih0    = (const float*)d_in[2];
  const float* W_hh0    = (const float*)d_in[3];
  const float* b_ih0    = (const float*)d_in[4];
  const float* b_hh0    = (const float*)d_in[5];
  const float* W_ih1    = (const float*)d_in[6];
  const float* W_hh1    = (const float*)d_in[7];
  const float* b_ih1    = (const float*)d_in[8];
  const float* b_hh1    = (const float*)d_in[9];
  const float* pm       = (const float*)d_in[10];
  const float* Wum      = (const float*)d_in[11];
  const float* Wvm      = (const float*)d_in[12];
  const float* Wup      = (const float*)d_in[13];
  const float* Wvp      = (const float*)d_in[14];
  const float* W_hyb    = (const float*)d_in[15];
  const float* b_hyb    = (const float*)d_in[16];
  const float* W_act    = (const float*)d_in[17];
  const float* b_act    = (const float*)d_in[18];
  const float* W_inact  = (const float*)d_in[19];
  const float* b_inact  = (const float*)d_in[20];
  const float* Wphin    = (const float*)d_in[21];
  const float* aphi     = (const float*)d_in[22];
  const float* Won      = (const float*)d_in[23];
  const float* Weo      = (const float*)d_in[24];
  const float* Wi       = (const float*)d_in[25];
  const float* bi       = (const float*)d_in[26];
  float* out = (float*)d_out;

  char* base = (char*)d_ws;
  size_t off = 0;
  auto take = [&](size_t bytes) -> char* {
    char* p = base + off;
    off += (bytes + 255) & ~(size_t)255;
    return p;
  };
  __fp16* pre1   = (__fp16*)take((size_t)TC * 8 * 32 * 512);           // 32MB
  __fp16* pre2   = (__fp16*)take((size_t)TC * 8 * 32 * 512);           // 32MB
  __fp16* h1ring = (__fp16*)take((size_t)2 * TC * 8 * 2048 * 2);       // 16MB
  __fp16* wih0h  = (__fp16*)take((size_t)512 * 128 * 2);
  __fp16* wih1h  = (__fp16*)take((size_t)512 * 128 * 2);
  __fp16* whh0h  = (__fp16*)take((size_t)512 * 128 * 2);
  __fp16* whh1h  = (__fp16*)take((size_t)512 * 128 * 2);
  __fp16* hs1    = (__fp16*)take((size_t)128 * 128 * 2);
  float* c1s     = (float*)take((size_t)128 * 128 * 4);
  __fp16* hs2    = (__fp16*)take((size_t)128 * 128 * 2);
  float* c2s     = (float*)take((size_t)128 * 128 * 4);
  float* pbuf  = (float*)take((size_t)NNODE * 128 * 4);
  float* nmat  = (float*)take((size_t)NNODE * 256 * 4);
  float* Amat  = (float*)take((size_t)NNODE * 192 * 4);
  float* Bmat  = (float*)take((size_t)NNODE * 192 * 4);
  float* Cmat  = (float*)take((size_t)NNODE * 256 * 4);
  float* Dmat  = (float*)take((size_t)NNODE * 256 * 4);
  float* Qmat  = (float*)take((size_t)NNODE * 256 * 4);
  float* Rmat  = (float*)take((size_t)NNODE * 256 * 4);
  float* phiT  = (float*)take((size_t)NNODE * NNODE * 4);
  float* alpha = (float*)take((size_t)NNODE * NNODE * 4);
  float* T1    = (float*)take((size_t)NNODE * 256 * 4);
  float* Spart = (float*)take((size_t)NNODE * 256 * 4);
  float* nrm   = (float*)take((size_t)NNODE * 4);
  float* vvec  = (float*)take(256 * 4);
  float* misc  = (float*)take(8 * 4);

  hipMemsetAsync(vvec, 0, 1024 + 32, stream);

  f32_to_f16_k<<<256, 256, 0, stream>>>(W_ih0, wih0h, 512 * 128);
  f32_to_f16_k<<<256, 256, 0, stream>>>(W_ih1, wih1h, 512 * 128);
  f32_to_f16_k<<<256, 256, 0, stream>>>(W_hh0, whh0h, 512 * 128);
  f32_to_f16_k<<<256, 256, 0, stream>>>(W_hh1, whh1h, 512 * 128);

  const size_t ringslot = (size_t)TC * 8 * 2048;   // f16 units
  const int gpb = (TC / TGB) * 8;                  // 256 blocks per projection
  for (int c = 0; c <= NCH; c++){
    const int n1 = (c < NCH) ? gpb : 0;
    const int n2 = (c >= 1) ? gpb : 0;
    if (n1 + n2 > 0)
      gateproj<<<n1 + n2, 256, 0, stream>>>(x, h1ring + (size_t)((c - 1) & 1) * ringslot,
                                            wih0h, wih1h,
                                            b_ih0, b_hh0, b_ih1, b_hh1,
                                            pre1, pre2, n1, c * TC);
    lstm_scan<<<16, 512, 0, stream>>>(pre1, pre2, h1ring, whh0h, whh1h,
                                      hs1, c1s, hs2, c2s, pbuf, c);
  }

  node_mlp<<<NNODE, 256, 0, stream>>>(x_tag, pm, Wvm, Wup, W_hyb, b_hyb,
                                      W_act, b_act, W_inact, b_inact, pbuf, nmat);
  node_proj<<<NNODE, 256, 0, stream>>>(nmat, Wphin, Won, Weo, Amat, Bmat, Cmat, Dmat, Qmat, Rmat);
  phi_kernel<<<NNODE, 128, 0, stream>>>(Amat, Bmat, aphi, phiT);
  alpha_kernel<<<NNODE, 128, 0, stream>>>(phiT, x_tag, alpha);
  att_sum<<<NNODE, 256, 0, stream>>>(alpha, Cmat, Dmat, Qmat, Rmat, nmat, T1, Spart, nrm);
  finalize_node<<<NNODE, 256, 0, stream>>>(T1, Spart, Weo, nmat, x_tag, Wi, bi, nrm, vvec, out);
  ort_kernel<<<128, 128, 0, stream>>>(Wum, Wvm, Wup, Wvp, misc);
  finalize_scalars<<<1, 256, 0, stream>>>(misc, vvec, out);
}